// Round 7
// baseline (4115.383 us; speedup 1.0000x reference)
//
#include <hip/hip_runtime.h>
#include <hip/hip_bf16.h>
#include <stdint.h>

// GRU-style LanguageEncoder: T=64, B=256, VOCAB=32000, D=512, H=1024.
// Reference semantics: a = tanh(a_x + (r * h) @ w_h_a + b_a)  ((r*h) BEFORE matmul).
// Structure:
//   k_gather    : words_bf16[t*B+b][d] = bf16(embed[x]*(x>0))
//   k_transpose : w_i -> wit (3072x512) bf16 ; w_h -> wht (3072x1024) bf16
//   k_zero      : zero h buffer + barrier flags
//   k_gemm_gx   : gx = words @ w_i + b  (16384x3072, bf16), 128x128 MFMA tile
//   k_recur     : persistent 64-block x 1024-thread kernel, 64 steps, 2 phases/step.
//                 R2: RMW counter + fences -> 33us/phase. R3: flag array + fences
//                 -> 21.5us/phase. R6: fenceless (RMW writes at L3 coherence
//                 point, relaxed sc1 reads) -> 16.4us/phase, still latency-bound
//                 (1 wave/SIMD, 4B loads, 256-block skew).
//                 R7: fold the 4 m-groups into one block (same jb -> SAME Wh
//                 slice): 64 blocks x 16 waves = 4 waves/SIMD TLP, uint64
//                 coherent loads (half the count), uint64 exchange stores
//                 (quarter the RMWs), single 64-block barrier domain.

#define TT 64
#define BB 256
#define DD 512
#define HH 1024
#define N3H 3072

using frag  = __attribute__((ext_vector_type(8))) short;   // 8 bf16 (4 VGPRs)
using f32x4 = __attribute__((ext_vector_type(4))) float;   // MFMA accumulator

__device__ __forceinline__ uint16_t f2b(float f) {
    uint32_t u = __builtin_bit_cast(uint32_t, f);
    uint32_t r = u + 0x7FFFu + ((u >> 16) & 1u);   // round-to-nearest-even
    return (uint16_t)(r >> 16);
}
__device__ __forceinline__ float b2f(uint16_t b) {
    uint32_t u = ((uint32_t)b) << 16;
    return __builtin_bit_cast(float, u);
}

// coherent (L3-read, L2-bypassing) 16B fragment load as 2 x 8B relaxed atomics
__device__ __forceinline__ frag load_frag_coh(const uint64_t* p) {
    union { uint64_t u[2]; frag f; } w;
    w.u[0] = __hip_atomic_load(p,     __ATOMIC_RELAXED, __HIP_MEMORY_SCOPE_AGENT);
    w.u[1] = __hip_atomic_load(p + 1, __ATOMIC_RELAXED, __HIP_MEMORY_SCOPE_AGENT);
    return w.f;
}

// ---------------- prep kernels ----------------

__global__ __launch_bounds__(256) void k_gather(const int* __restrict__ x,
                                                const float* __restrict__ embed,
                                                uint16_t* __restrict__ words) {
    int tid = blockIdx.x * 256 + threadIdx.x;
    int row = tid >> 6;
    int c8  = (tid & 63) << 3;
    int tok = x[row];
    float s = (tok > 0) ? 1.f : 0.f;
    const float4* src = (const float4*)(embed + (int64_t)tok * DD + c8);
    float4 v0 = src[0], v1 = src[1];
    float vals[8] = {v0.x, v0.y, v0.z, v0.w, v1.x, v1.y, v1.z, v1.w};
    union { uint16_t u[8]; uint4 q; } pk;
#pragma unroll
    for (int i = 0; i < 8; ++i) pk.u[i] = f2b(vals[i] * s);
    *(uint4*)(words + ((int64_t)row << 9) + c8) = pk.q;
}

// src (K x N) fp32 -> dst (N x K) bf16, 32x32 LDS tiles
__global__ void k_transpose(const float* __restrict__ src, uint16_t* __restrict__ dst,
                            int K, int N) {
    __shared__ float tile[32][33];
    int n0 = blockIdx.x * 32, k0 = blockIdx.y * 32;
    int tx = threadIdx.x, ty = threadIdx.y;   // (32, 8)
#pragma unroll
    for (int i = 0; i < 32; i += 8)
        tile[ty + i][tx] = src[(int64_t)(k0 + ty + i) * N + n0 + tx];
    __syncthreads();
#pragma unroll
    for (int i = 0; i < 32; i += 8)
        dst[(int64_t)(n0 + ty + i) * K + k0 + tx] = f2b(tile[tx][ty + i]);
}

__global__ void k_zero(uint4* p, int n16) {
    int i = blockIdx.x * blockDim.x + threadIdx.x;
    if (i < n16) p[i] = uint4{0u, 0u, 0u, 0u};
}

// ---------------- gx GEMM: 16384 x 3072 x 512 ----------------

__global__ __launch_bounds__(256) void k_gemm_gx(const uint16_t* __restrict__ A,
                                                 const uint16_t* __restrict__ BT,
                                                 const float* __restrict__ bias,
                                                 uint16_t* __restrict__ C) {
    __shared__ uint16_t As[128][72];
    __shared__ uint16_t Bs[128][72];
    int m0 = blockIdx.y * 128;
    int n0 = blockIdx.x * 128;
    int t = threadIdx.x;
    int wave = t >> 6, lane = t & 63, quad = lane >> 4, l16 = lane & 15;
    int wm = (wave & 1) * 64, wn = (wave >> 1) * 64;
    f32x4 acc[4][4] = {};

    int sr = t >> 1;
    int sc = (t & 1) * 32;

    for (int k0 = 0; k0 < DD; k0 += 64) {
        const uint4* ga = (const uint4*)(A + (int64_t)(m0 + sr) * DD + k0 + sc);
        uint4 a0 = ga[0], a1 = ga[1], a2 = ga[2], a3 = ga[3];
        const uint4* gb = (const uint4*)(BT + (int64_t)(n0 + sr) * DD + k0 + sc);
        uint4 b0 = gb[0], b1 = gb[1], b2 = gb[2], b3 = gb[3];
        __syncthreads();
        *(uint4*)&As[sr][sc]      = a0;
        *(uint4*)&As[sr][sc + 8]  = a1;
        *(uint4*)&As[sr][sc + 16] = a2;
        *(uint4*)&As[sr][sc + 24] = a3;
        *(uint4*)&Bs[sr][sc]      = b0;
        *(uint4*)&Bs[sr][sc + 8]  = b1;
        *(uint4*)&Bs[sr][sc + 16] = b2;
        *(uint4*)&Bs[sr][sc + 24] = b3;
        __syncthreads();
#pragma unroll
        for (int kk = 0; kk < 64; kk += 32) {
            frag af[4], bf[4];
#pragma unroll
            for (int mi = 0; mi < 4; ++mi)
                af[mi] = *(const frag*)&As[wm + mi * 16 + l16][kk + quad * 8];
#pragma unroll
            for (int ni = 0; ni < 4; ++ni)
                bf[ni] = *(const frag*)&Bs[wn + ni * 16 + l16][kk + quad * 8];
#pragma unroll
            for (int mi = 0; mi < 4; ++mi)
#pragma unroll
                for (int ni = 0; ni < 4; ++ni)
                    acc[mi][ni] = __builtin_amdgcn_mfma_f32_16x16x32_bf16(
                        af[mi], bf[ni], acc[mi][ni], 0, 0, 0);
        }
    }
#pragma unroll
    for (int ni = 0; ni < 4; ++ni) {
        int col = n0 + wn + ni * 16 + l16;
        float bv = bias[col];
#pragma unroll
        for (int mi = 0; mi < 4; ++mi)
#pragma unroll
            for (int r = 0; r < 4; ++r) {
                int row = m0 + wm + mi * 16 + quad * 4 + r;
                C[(int64_t)row * N3H + col] = f2b(acc[mi][ni][r] + bv);
            }
    }
}

// ---------------- recurrence ----------------
// grid = 64 blocks (one per j-strip), 1024 threads = 16 waves. Wave w owns batch
// rows w*16..w*16+15 for the block's 16-col strip (cols {j,H+j,2H+j} of w_h).
// LDS: Wh[48][1032] bf16 (99KB) shared by all 16 waves.
// Flags: one 4B slot per block, 64B apart.

__global__ __launch_bounds__(1024, 4) void k_recur(const uint16_t* __restrict__ gx,
                                                   const uint16_t* __restrict__ wht,
                                                   uint16_t* __restrict__ hbuf,
                                                   uint16_t* __restrict__ rhbuf,
                                                   unsigned int* __restrict__ bar,
                                                   float* __restrict__ out) {
    extern __shared__ uint16_t Wh[];           // 48 rows x 1032 (1024 + 8 pad)
    const int LDW = HH + 8;
    int jb = blockIdx.x;        // 0..63
    int j0 = jb * 16;
    int t = threadIdx.x, wave = t >> 6, lane = t & 63, quad = lane >> 4, l16 = lane & 15;

    // load w_h slice: gathered rows s*16+i  <-  wht row s*HH + j0 + i
    for (int c = t; c < 48 * 128; c += 1024) {
        int row = c >> 7;
        int off = (c & 127) << 3;
        int s = row >> 4, i = row & 15;
        *(uint4*)(Wh + row * LDW + off) =
            *(const uint4*)(wht + (int64_t)(s * HH + j0 + i) * HH + off);
    }
    __syncthreads();

    float hp[4]   = {0.f, 0.f, 0.f, 0.f};   // this lane's 4 rows x 1 col of h (fp32)
    float zg[4];
    float osum[4] = {0.f, 0.f, 0.f, 0.f};
    int brow = wave * 16 + quad * 4;         // C-layout base row (0..255)
    int jcol = j0 + l16;
    const int jc4 = j0 + (l16 & ~3);         // 4-col pack base
    unsigned int* flags = bar;               // 64 slots x 64B stride
    unsigned int phase = 0;

    // A-operand base (this lane's MFMA A rows), as uint64 index
    const int64_t aoff = (int64_t)(wave * 16 + l16) * HH + quad * 8;   // uint16 elems
    const uint64_t* h64  = (const uint64_t*)hbuf  + (aoff >> 2);
    const uint64_t* rh64 = (const uint64_t*)rhbuf + (aoff >> 2);

    // arrive: drain my data RMWs (syncthreads -> vmcnt(0)), then RMW my flag slot.
    auto bar_arrive = [&]() {
        __syncthreads();
        if (t == 0)
            (void)__hip_atomic_fetch_add(&flags[jb * 16], 1u, __ATOMIC_RELAXED,
                                         __HIP_MEMORY_SCOPE_AGENT);
    };
    // wait: wave0 polls all 64 slots in parallel with relaxed sc1 loads.
    auto bar_wait = [&](unsigned int ph) {
        if (wave == 0) {
            long guard = 0;
            for (;;) {
                unsigned int v = __hip_atomic_load(&flags[lane * 16], __ATOMIC_RELAXED,
                                                   __HIP_MEMORY_SCOPE_AGENT);
                if (__all((int)(v >= ph))) break;
                __builtin_amdgcn_s_sleep(2);
                if (++guard > (1L << 13)) break;   // fail fast (absmax), never wedge
            }
        }
        __syncthreads();
    };

    // pack this lane's value with lanes l16^1, l16^2 -> one uint64 (4 adjacent
    // cols) exchanged to the coherence point by the (l16%4==0) lane.
    auto store4 = [&](uint16_t* base, int r, uint32_t mine) {
        uint32_t p2 = mine | (((uint32_t)__shfl_xor((int)mine, 1)) << 16);
        uint32_t hi = (uint32_t)__shfl_xor((int)p2, 2);
        if ((l16 & 3) == 0) {
            uint64_t p4 = (uint64_t)p2 | ((uint64_t)hi << 32);
            uint64_t* dst = (uint64_t*)base + (int64_t)(brow + r) * (HH / 4) + (jc4 >> 2);
            (void)__hip_atomic_exchange(dst, p4, __ATOMIC_RELAXED, __HIP_MEMORY_SCOPE_AGENT);
        }
    };

    for (int step = 0; step < TT; ++step) {
        // ---- barrier: h(step) fully written by all blocks ----
        if (step > 0) bar_arrive();

        // prefetch this step's gx scalars (immutable, normal cached loads);
        // issued between arrive and wait so latency hides under the poll
        uint16_t gzv[4], grv[4], gav[4];
        {
            const uint16_t* gxrow = gx + (int64_t)step * BB * N3H;
#pragma unroll
            for (int r = 0; r < 4; ++r) {
                const uint16_t* g = gxrow + (int64_t)(brow + r) * N3H + jcol;
                gzv[r] = g[0]; grv[r] = g[HH]; gav[r] = g[2 * HH];
            }
        }

        if (step > 0) bar_wait(++phase);

        // ---- phase Z: h @ w_h_zr (acc0 = z-col, acc1 = r-col) ----
        {
            f32x4 acc0 = {}, acc1 = {};
#pragma unroll 8
            for (int kk = 0; kk < 32; ++kk) {
                frag a  = load_frag_coh(h64 + kk * 8);
                frag b0 = *(const frag*)(Wh + (l16)      * LDW + kk * 32 + quad * 8);
                frag b1 = *(const frag*)(Wh + (16 + l16) * LDW + kk * 32 + quad * 8);
                acc0 = __builtin_amdgcn_mfma_f32_16x16x32_bf16(a, b0, acc0, 0, 0, 0);
                acc1 = __builtin_amdgcn_mfma_f32_16x16x32_bf16(a, b1, acc1, 0, 0, 0);
            }
#pragma unroll
            for (int r = 0; r < 4; ++r) {
                float zp = b2f(gzv[r]) + acc0[r];        // bias folded into gx
                float rp = b2f(grv[r]) + acc1[r];
                float z  = 1.f / (1.f + __expf(-zp));
                float rg = 1.f / (1.f + __expf(-rp));
                zg[r] = z;
                store4(rhbuf, r, f2b(rg * hp[r]));
            }
        }

        // ---- barrier: rh fully written by all blocks ----
        bar_arrive();
        bar_wait(++phase);

        // ---- phase A: rh @ w_h_a (acc2), gate + h update ----
        {
            f32x4 acc2 = {};
#pragma unroll 8
            for (int kk = 0; kk < 32; ++kk) {
                frag a  = load_frag_coh(rh64 + kk * 8);
                frag b2 = *(const frag*)(Wh + (32 + l16) * LDW + kk * 32 + quad * 8);
                acc2 = __builtin_amdgcn_mfma_f32_16x16x32_bf16(a, b2, acc2, 0, 0, 0);
            }
#pragma unroll
            for (int r = 0; r < 4; ++r) {
                float a  = tanhf(b2f(gav[r]) + acc2[r]);
                float hn = (1.f - zg[r]) * hp[r] + zg[r] * a;
                osum[r] += hn;
                hp[r] = hn;
                store4(hbuf, r, f2b(hn));
            }
        }
    }
#pragma unroll
    for (int r = 0; r < 4; ++r)
        out[(int64_t)(brow + r) * HH + jcol] = osum[r];
}

// ---------------- launch ----------------

extern "C" void kernel_launch(void* const* d_in, const int* in_sizes, int n_in,
                              void* d_out, int out_size, void* d_ws, size_t ws_size,
                              hipStream_t stream) {
    const int*   x     = (const int*)d_in[0];
    const float* embed = (const float*)d_in[1];
    const float* w_i   = (const float*)d_in[2];
    const float* w_h   = (const float*)d_in[3];
    const float* bias  = (const float*)d_in[4];
    float* out = (float*)d_out;

    char* ws = (char*)d_ws;
    uint16_t* gx    = (uint16_t*)(ws);                 // 16384*3072*2 = 100663296
    uint16_t* wit   = (uint16_t*)(ws + 100663296);     // 3072*512*2  =   3145728
    uint16_t* wht   = (uint16_t*)(ws + 103809024);     // 3072*1024*2 =   6291456
    uint16_t* words = (uint16_t*)(ws + 110100480);     // 16384*512*2 =  16777216
    uint16_t* hbuf  = (uint16_t*)(ws + 126877696);     // 256*1024*2  =    524288
    uint16_t* rhbuf = (uint16_t*)(ws + 127401984);     // 256*1024*2  =    524288
    unsigned int* flags = (unsigned int*)(ws + 127926272); // 64*64B = 4096 (16K zeroed)

    k_gather<<<4096, 256, 0, stream>>>(x, embed, words);
    k_transpose<<<dim3(96, 16), dim3(32, 8), 0, stream>>>(w_i, wit, DD, N3H);
    k_transpose<<<dim3(96, 32), dim3(32, 8), 0, stream>>>(w_h, wht, HH, N3H);
    // zero hbuf + rhbuf + flags (contiguous 1048576 + 16384 bytes)
    k_zero<<<261, 256, 0, stream>>>((uint4*)(ws + 126877696), (1048576 + 16384) / 16);
    k_gemm_gx<<<dim3(24, 128), 256, 0, stream>>>(words, wit, bias, gx);
    k_recur<<<64, 1024, 48 * (HH + 8) * 2, stream>>>(gx, wht, hbuf, rhbuf, flags, out);
}

// Round 8
// 1816.407 us; speedup vs baseline: 2.2657x; 2.2657x over previous
//
#include <hip/hip_runtime.h>
#include <hip/hip_bf16.h>
#include <stdint.h>

// GRU-style LanguageEncoder: T=64, B=256, VOCAB=32000, D=512, H=1024.
// Reference semantics: a = tanh(a_x + (r * h) @ w_h_a + b_a)  ((r*h) BEFORE matmul).
// Structure:
//   k_gather    : words_bf16[t*B+b][d] = bf16(embed[x]*(x>0))
//   k_transpose : w_i -> wit (3072x512) bf16 ; w_h -> wht (3072x1024) bf16
//   k_zero      : zero h buffer + barrier flags
//   k_gemm_gx   : gx = words @ w_i + b  (16384x3072, bf16), 128x128 MFMA tile
//   k_recur     : persistent 256-block kernel, 64 steps, 2 phases/step.
//   History: R2 fences+counter 33us/phase; R3 fences+flags 21.5; R6 fenceless
//   (all h/rh traffic on the L2-bypassing sc0sc1 atomic path) 16.4; R7 64 fat
//   blocks REGRESSED (atomic-path reads from 64 CUs serialize; 4x gx overfetch).
//   R8: R6 geometry, but h/rh READS are plain cached b128 loads (L2 absorbs the
//   64x broadcast; L3 only fills ~4MB/phase) + acquire-only agent fence
//   (buffer_inv, no wbl2) after each barrier wait. WRITES stay as uint64
//   atomic-exchange RMWs (performed at L3, never dirty L2 -> release side
//   needs no writeback). Flag barrier mechanics unchanged from R6.

#define TT 64
#define BB 256
#define DD 512
#define HH 1024
#define N3H 3072

using frag  = __attribute__((ext_vector_type(8))) short;   // 8 bf16 (4 VGPRs)
using f32x4 = __attribute__((ext_vector_type(4))) float;   // MFMA accumulator

__device__ __forceinline__ uint16_t f2b(float f) {
    uint32_t u = __builtin_bit_cast(uint32_t, f);
    uint32_t r = u + 0x7FFFu + ((u >> 16) & 1u);   // round-to-nearest-even
    return (uint16_t)(r >> 16);
}
__device__ __forceinline__ float b2f(uint16_t b) {
    uint32_t u = ((uint32_t)b) << 16;
    return __builtin_bit_cast(float, u);
}

// ---------------- prep kernels ----------------

__global__ __launch_bounds__(256) void k_gather(const int* __restrict__ x,
                                                const float* __restrict__ embed,
                                                uint16_t* __restrict__ words) {
    int tid = blockIdx.x * 256 + threadIdx.x;
    int row = tid >> 6;
    int c8  = (tid & 63) << 3;
    int tok = x[row];
    float s = (tok > 0) ? 1.f : 0.f;
    const float4* src = (const float4*)(embed + (int64_t)tok * DD + c8);
    float4 v0 = src[0], v1 = src[1];
    float vals[8] = {v0.x, v0.y, v0.z, v0.w, v1.x, v1.y, v1.z, v1.w};
    union { uint16_t u[8]; uint4 q; } pk;
#pragma unroll
    for (int i = 0; i < 8; ++i) pk.u[i] = f2b(vals[i] * s);
    *(uint4*)(words + ((int64_t)row << 9) + c8) = pk.q;
}

// src (K x N) fp32 -> dst (N x K) bf16, 32x32 LDS tiles
__global__ void k_transpose(const float* __restrict__ src, uint16_t* __restrict__ dst,
                            int K, int N) {
    __shared__ float tile[32][33];
    int n0 = blockIdx.x * 32, k0 = blockIdx.y * 32;
    int tx = threadIdx.x, ty = threadIdx.y;   // (32, 8)
#pragma unroll
    for (int i = 0; i < 32; i += 8)
        tile[ty + i][tx] = src[(int64_t)(k0 + ty + i) * N + n0 + tx];
    __syncthreads();
#pragma unroll
    for (int i = 0; i < 32; i += 8)
        dst[(int64_t)(n0 + ty + i) * K + k0 + tx] = f2b(tile[tx][ty + i]);
}

__global__ void k_zero(uint4* p, int n16) {
    int i = blockIdx.x * blockDim.x + threadIdx.x;
    if (i < n16) p[i] = uint4{0u, 0u, 0u, 0u};
}

// ---------------- gx GEMM: 16384 x 3072 x 512 ----------------

__global__ __launch_bounds__(256) void k_gemm_gx(const uint16_t* __restrict__ A,
                                                 const uint16_t* __restrict__ BT,
                                                 const float* __restrict__ bias,
                                                 uint16_t* __restrict__ C) {
    __shared__ uint16_t As[128][72];
    __shared__ uint16_t Bs[128][72];
    int m0 = blockIdx.y * 128;
    int n0 = blockIdx.x * 128;
    int t = threadIdx.x;
    int wave = t >> 6, lane = t & 63, quad = lane >> 4, l16 = lane & 15;
    int wm = (wave & 1) * 64, wn = (wave >> 1) * 64;
    f32x4 acc[4][4] = {};

    int sr = t >> 1;
    int sc = (t & 1) * 32;

    for (int k0 = 0; k0 < DD; k0 += 64) {
        const uint4* ga = (const uint4*)(A + (int64_t)(m0 + sr) * DD + k0 + sc);
        uint4 a0 = ga[0], a1 = ga[1], a2 = ga[2], a3 = ga[3];
        const uint4* gb = (const uint4*)(BT + (int64_t)(n0 + sr) * DD + k0 + sc);
        uint4 b0 = gb[0], b1 = gb[1], b2 = gb[2], b3 = gb[3];
        __syncthreads();
        *(uint4*)&As[sr][sc]      = a0;
        *(uint4*)&As[sr][sc + 8]  = a1;
        *(uint4*)&As[sr][sc + 16] = a2;
        *(uint4*)&As[sr][sc + 24] = a3;
        *(uint4*)&Bs[sr][sc]      = b0;
        *(uint4*)&Bs[sr][sc + 8]  = b1;
        *(uint4*)&Bs[sr][sc + 16] = b2;
        *(uint4*)&Bs[sr][sc + 24] = b3;
        __syncthreads();
#pragma unroll
        for (int kk = 0; kk < 64; kk += 32) {
            frag af[4], bf[4];
#pragma unroll
            for (int mi = 0; mi < 4; ++mi)
                af[mi] = *(const frag*)&As[wm + mi * 16 + l16][kk + quad * 8];
#pragma unroll
            for (int ni = 0; ni < 4; ++ni)
                bf[ni] = *(const frag*)&Bs[wn + ni * 16 + l16][kk + quad * 8];
#pragma unroll
            for (int mi = 0; mi < 4; ++mi)
#pragma unroll
                for (int ni = 0; ni < 4; ++ni)
                    acc[mi][ni] = __builtin_amdgcn_mfma_f32_16x16x32_bf16(
                        af[mi], bf[ni], acc[mi][ni], 0, 0, 0);
        }
    }
#pragma unroll
    for (int ni = 0; ni < 4; ++ni) {
        int col = n0 + wn + ni * 16 + l16;
        float bv = bias[col];
#pragma unroll
        for (int mi = 0; mi < 4; ++mi)
#pragma unroll
            for (int r = 0; r < 4; ++r) {
                int row = m0 + wm + mi * 16 + quad * 4 + r;
                C[(int64_t)row * N3H + col] = f2b(acc[mi][ni][r] + bv);
            }
    }
}

// ---------------- recurrence ----------------
// grid (mg=4, jb=64): linear id = mg + 4*jb -> each m-group's 64 blocks sit on
// XCDs {mg, mg+4} (i%8 round-robin). LDS: Wh[48][1032] bf16 (99KB).
// Flags: one 4B slot per block, 64B apart; group mg owns bar[mg*1024 + jb*16].

__global__ __launch_bounds__(256, 1) void k_recur(const uint16_t* __restrict__ gx,
                                                  const uint16_t* __restrict__ wht,
                                                  uint16_t* __restrict__ hbuf,
                                                  uint16_t* __restrict__ rhbuf,
                                                  unsigned int* __restrict__ bar,
                                                  float* __restrict__ out) {
    extern __shared__ uint16_t Wh[];           // 48 rows x 1032 (1024 + 8 pad)
    const int LDW = HH + 8;
    int mg = blockIdx.x;        // 0..3  (fast dim -> XCD pairing)
    int jb = blockIdx.y;        // 0..63
    int j0 = jb * 16;
    int m0 = mg * 64;
    int t = threadIdx.x, wave = t >> 6, lane = t & 63, quad = lane >> 4, l16 = lane & 15;

    // load w_h slice: gathered rows s*16+i  <-  wht row s*HH + j0 + i
    for (int c = t; c < 48 * 128; c += 256) {
        int row = c >> 7;
        int off = (c & 127) << 3;
        int s = row >> 4, i = row & 15;
        *(uint4*)(Wh + row * LDW + off) =
            *(const uint4*)(wht + (int64_t)(s * HH + j0 + i) * HH + off);
    }
    __syncthreads();

    float hp[4]   = {0.f, 0.f, 0.f, 0.f};
    float zg[4];
    float osum[4] = {0.f, 0.f, 0.f, 0.f};
    int brow = m0 + wave * 16 + quad * 4;
    int jcol = j0 + l16;
    const int jc4 = j0 + (l16 & ~3);         // 4-col pack base
    unsigned int* flags = bar + mg * 1024;   // 64 slots x 64B stride
    unsigned int phase = 0;

    // A-operand base (this lane's MFMA A rows) - plain cached reads
    const uint16_t* harow  = hbuf  + (int64_t)(m0 + wave * 16 + l16) * HH + quad * 8;
    const uint16_t* rharow = rhbuf + (int64_t)(m0 + wave * 16 + l16) * HH + quad * 8;

    // arrive: drain my data RMWs (syncthreads -> vmcnt(0)), then RMW my flag slot.
    auto bar_arrive = [&]() {
        __syncthreads();
        if (t == 0)
            (void)__hip_atomic_fetch_add(&flags[jb * 16], 1u, __ATOMIC_RELAXED,
                                         __HIP_MEMORY_SCOPE_AGENT);
    };
    // wait: wave0 polls all 64 slots in parallel with relaxed sc1 loads; then all
    // threads issue an acquire-only agent fence (buffer_inv + L1 inv, NO wbl2) so
    // the subsequent plain cached loads of h/rh can't see stale L1/L2 lines.
    auto bar_wait = [&](unsigned int ph) {
        if (wave == 0) {
            long guard = 0;
            for (;;) {
                unsigned int v = __hip_atomic_load(&flags[lane * 16], __ATOMIC_RELAXED,
                                                   __HIP_MEMORY_SCOPE_AGENT);
                if (__all((int)(v >= ph))) break;
                __builtin_amdgcn_s_sleep(2);
                if (++guard > (1L << 13)) break;   // fail fast (absmax), never wedge
            }
        }
        __syncthreads();
        __builtin_amdgcn_fence(__ATOMIC_ACQUIRE, "agent");   // invalidate, no writeback
    };

    // pack this lane's value with lanes l16^1, l16^2 -> one uint64 (4 adjacent
    // cols) exchanged to the coherence point by the (l16%4==0) lane.
    auto store4 = [&](uint16_t* base, int r, uint32_t mine) {
        uint32_t p2 = mine | (((uint32_t)__shfl_xor((int)mine, 1)) << 16);
        uint32_t hi = (uint32_t)__shfl_xor((int)p2, 2);
        if ((l16 & 3) == 0) {
            uint64_t p4 = (uint64_t)p2 | ((uint64_t)hi << 32);
            uint64_t* dst = (uint64_t*)base + (int64_t)(brow + r) * (HH / 4) + (jc4 >> 2);
            (void)__hip_atomic_exchange(dst, p4, __ATOMIC_RELAXED, __HIP_MEMORY_SCOPE_AGENT);
        }
    };

    for (int step = 0; step < TT; ++step) {
        // ---- barrier: h(step) fully written by all blocks in m-group ----
        if (step > 0) bar_arrive();

        // prefetch this step's gx scalars (immutable, normal cached loads);
        // issued between arrive and wait so latency hides under the poll
        uint16_t gzv[4], grv[4], gav[4];
        {
            const uint16_t* gxrow = gx + (int64_t)step * BB * N3H;
#pragma unroll
            for (int r = 0; r < 4; ++r) {
                const uint16_t* g = gxrow + (int64_t)(brow + r) * N3H + jcol;
                gzv[r] = g[0]; grv[r] = g[HH]; gav[r] = g[2 * HH];
            }
        }

        if (step > 0) bar_wait(++phase);

        // ---- phase Z: h @ w_h_zr (acc0 = z-col, acc1 = r-col) ----
        {
            f32x4 acc0 = {}, acc1 = {};
#pragma unroll 8
            for (int kk = 0; kk < 32; ++kk) {
                frag a  = *(const frag*)(harow + kk * 32);
                frag b0 = *(const frag*)(Wh + (l16)      * LDW + kk * 32 + quad * 8);
                frag b1 = *(const frag*)(Wh + (16 + l16) * LDW + kk * 32 + quad * 8);
                acc0 = __builtin_amdgcn_mfma_f32_16x16x32_bf16(a, b0, acc0, 0, 0, 0);
                acc1 = __builtin_amdgcn_mfma_f32_16x16x32_bf16(a, b1, acc1, 0, 0, 0);
            }
#pragma unroll
            for (int r = 0; r < 4; ++r) {
                float zp = b2f(gzv[r]) + acc0[r];        // bias folded into gx
                float rp = b2f(grv[r]) + acc1[r];
                float z  = 1.f / (1.f + __expf(-zp));
                float rg = 1.f / (1.f + __expf(-rp));
                zg[r] = z;
                store4(rhbuf, r, f2b(rg * hp[r]));
            }
        }

        // ---- barrier: rh fully written by all blocks in m-group ----
        bar_arrive();
        bar_wait(++phase);

        // ---- phase A: rh @ w_h_a (acc2), gate + h update ----
        {
            f32x4 acc2 = {};
#pragma unroll 8
            for (int kk = 0; kk < 32; ++kk) {
                frag a  = *(const frag*)(rharow + kk * 32);
                frag b2 = *(const frag*)(Wh + (32 + l16) * LDW + kk * 32 + quad * 8);
                acc2 = __builtin_amdgcn_mfma_f32_16x16x32_bf16(a, b2, acc2, 0, 0, 0);
            }
#pragma unroll
            for (int r = 0; r < 4; ++r) {
                float a  = tanhf(b2f(gav[r]) + acc2[r]);
                float hn = (1.f - zg[r]) * hp[r] + zg[r] * a;
                osum[r] += hn;
                hp[r] = hn;
                store4(hbuf, r, f2b(hn));
            }
        }
    }
#pragma unroll
    for (int r = 0; r < 4; ++r)
        out[(int64_t)(brow + r) * HH + jcol] = osum[r];
}

// ---------------- launch ----------------

extern "C" void kernel_launch(void* const* d_in, const int* in_sizes, int n_in,
                              void* d_out, int out_size, void* d_ws, size_t ws_size,
                              hipStream_t stream) {
    const int*   x     = (const int*)d_in[0];
    const float* embed = (const float*)d_in[1];
    const float* w_i   = (const float*)d_in[2];
    const float* w_h   = (const float*)d_in[3];
    const float* bias  = (const float*)d_in[4];
    float* out = (float*)d_out;

    char* ws = (char*)d_ws;
    uint16_t* gx    = (uint16_t*)(ws);                 // 16384*3072*2 = 100663296
    uint16_t* wit   = (uint16_t*)(ws + 100663296);     // 3072*512*2  =   3145728
    uint16_t* wht   = (uint16_t*)(ws + 103809024);     // 3072*1024*2 =   6291456
    uint16_t* words = (uint16_t*)(ws + 110100480);     // 16384*512*2 =  16777216
    uint16_t* hbuf  = (uint16_t*)(ws + 126877696);     // 256*1024*2  =    524288
    uint16_t* rhbuf = (uint16_t*)(ws + 127401984);     // 256*1024*2  =    524288
    unsigned int* flags = (unsigned int*)(ws + 127926272); // 4*1024*4 = 16384

    k_gather<<<4096, 256, 0, stream>>>(x, embed, words);
    k_transpose<<<dim3(96, 16), dim3(32, 8), 0, stream>>>(w_i, wit, DD, N3H);
    k_transpose<<<dim3(96, 32), dim3(32, 8), 0, stream>>>(w_h, wht, HH, N3H);
    // zero hbuf + rhbuf + flags (contiguous 1048576 + 16384 bytes)
    k_zero<<<261, 256, 0, stream>>>((uint4*)(ws + 126877696), (1048576 + 16384) / 16);
    k_gemm_gx<<<dim3(24, 128), 256, 0, stream>>>(words, wit, bias, gx);
    k_recur<<<dim3(4, 64), 256, 48 * (HH + 8) * 2, stream>>>(gx, wht, hbuf, rhbuf, flags, out);
}

// Round 10
// 968.330 us; speedup vs baseline: 4.2500x; 1.8758x over previous
//
#include <hip/hip_runtime.h>
#include <hip/hip_bf16.h>
#include <stdint.h>

// GRU-style LanguageEncoder: T=64, B=256, VOCAB=32000, D=512, H=1024.
// Reference semantics: a = tanh(a_x + (r * h) @ w_h_a + b_a)  ((r*h) BEFORE matmul).
// Structure:
//   k_gather    : words_bf16[t*B+b][d] = bf16(embed[x]*(x>0))
//   k_transpose : w_i -> wit (3072x512) bf16 ; w_h -> wht (3072x1024) bf16
//   k_zero      : zero h buffer + barrier flags
//   k_gemm_gx   : gx = words @ w_i + b  (16384x3072, bf16), 128x128 MFMA tile
//   k_recur     : persistent 256-block kernel, 64 steps, 2 phases/step.
//   History (per-phase): R2 RMW-chain+fences 33us; R3 flags+fences 21.5
//   (-8.7 = wbl2); R6 fenceless w/ 4B ATOMIC reads 16.4 (atomic-pipe
//   op-rate-bound); R7 64 fat blocks 26 (regression); R8 flags + acquire-inv +
//   cached reads 12.8 (inv L2-walk ~5us/phase remains).
//   R9/R10: NO fences at all. h/rh reads are PLAIN global_load_dwordx4 sc0 sc1
//   (inline asm; NOTE gfx950 operand order: offset BEFORE cache flags):
//   L1/L2-bypassing, performed at L3 like atomic loads, but at line rate on
//   the normal path - no atomic pipe, no inv needed, gx stays L2-warm.
//   Writes stay uint64 exchange RMWs (L3-performed, proven R6-R8).
//   Flag barrier mechanics unchanged.

#define TT 64
#define BB 256
#define DD 512
#define HH 1024
#define N3H 3072

using frag  = __attribute__((ext_vector_type(8))) short;   // 8 bf16 (4 VGPRs)
using f32x4 = __attribute__((ext_vector_type(4))) float;   // MFMA accumulator

__device__ __forceinline__ uint16_t f2b(float f) {
    uint32_t u = __builtin_bit_cast(uint32_t, f);
    uint32_t r = u + 0x7FFFu + ((u >> 16) & 1u);   // round-to-nearest-even
    return (uint16_t)(r >> 16);
}
__device__ __forceinline__ float b2f(uint16_t b) {
    uint32_t u = ((uint32_t)b) << 16;
    return __builtin_bit_cast(float, u);
}

// 8 x 16B L3-coherent plain loads (sc0 sc1: bypass L1/L2, read at the
// coherence point) from consecutive 64B-strided addresses, then drain.
// gfx950 asm operand order: offset:N comes BEFORE the cache flags.
__device__ __forceinline__ void load8_l3(const uint16_t* p, frag* f) {
    asm volatile(
        "global_load_dwordx4 %0, %8, off sc0 sc1\n\t"
        "global_load_dwordx4 %1, %8, off offset:64 sc0 sc1\n\t"
        "global_load_dwordx4 %2, %8, off offset:128 sc0 sc1\n\t"
        "global_load_dwordx4 %3, %8, off offset:192 sc0 sc1\n\t"
        "global_load_dwordx4 %4, %8, off offset:256 sc0 sc1\n\t"
        "global_load_dwordx4 %5, %8, off offset:320 sc0 sc1\n\t"
        "global_load_dwordx4 %6, %8, off offset:384 sc0 sc1\n\t"
        "global_load_dwordx4 %7, %8, off offset:448 sc0 sc1\n\t"
        "s_waitcnt vmcnt(0)"
        : "=&v"(f[0]), "=&v"(f[1]), "=&v"(f[2]), "=&v"(f[3]),
          "=&v"(f[4]), "=&v"(f[5]), "=&v"(f[6]), "=&v"(f[7])
        : "v"(p)
        : "memory");
}

// ---------------- prep kernels ----------------

__global__ __launch_bounds__(256) void k_gather(const int* __restrict__ x,
                                                const float* __restrict__ embed,
                                                uint16_t* __restrict__ words) {
    int tid = blockIdx.x * 256 + threadIdx.x;
    int row = tid >> 6;
    int c8  = (tid & 63) << 3;
    int tok = x[row];
    float s = (tok > 0) ? 1.f : 0.f;
    const float4* src = (const float4*)(embed + (int64_t)tok * DD + c8);
    float4 v0 = src[0], v1 = src[1];
    float vals[8] = {v0.x, v0.y, v0.z, v0.w, v1.x, v1.y, v1.z, v1.w};
    union { uint16_t u[8]; uint4 q; } pk;
#pragma unroll
    for (int i = 0; i < 8; ++i) pk.u[i] = f2b(vals[i] * s);
    *(uint4*)(words + ((int64_t)row << 9) + c8) = pk.q;
}

// src (K x N) fp32 -> dst (N x K) bf16, 32x32 LDS tiles
__global__ void k_transpose(const float* __restrict__ src, uint16_t* __restrict__ dst,
                            int K, int N) {
    __shared__ float tile[32][33];
    int n0 = blockIdx.x * 32, k0 = blockIdx.y * 32;
    int tx = threadIdx.x, ty = threadIdx.y;   // (32, 8)
#pragma unroll
    for (int i = 0; i < 32; i += 8)
        tile[ty + i][tx] = src[(int64_t)(k0 + ty + i) * N + n0 + tx];
    __syncthreads();
#pragma unroll
    for (int i = 0; i < 32; i += 8)
        dst[(int64_t)(n0 + ty + i) * K + k0 + tx] = f2b(tile[tx][ty + i]);
}

__global__ void k_zero(uint4* p, int n16) {
    int i = blockIdx.x * blockDim.x + threadIdx.x;
    if (i < n16) p[i] = uint4{0u, 0u, 0u, 0u};
}

// ---------------- gx GEMM: 16384 x 3072 x 512 ----------------

__global__ __launch_bounds__(256) void k_gemm_gx(const uint16_t* __restrict__ A,
                                                 const uint16_t* __restrict__ BT,
                                                 const float* __restrict__ bias,
                                                 uint16_t* __restrict__ C) {
    __shared__ uint16_t As[128][72];
    __shared__ uint16_t Bs[128][72];
    int m0 = blockIdx.y * 128;
    int n0 = blockIdx.x * 128;
    int t = threadIdx.x;
    int wave = t >> 6, lane = t & 63, quad = lane >> 4, l16 = lane & 15;
    int wm = (wave & 1) * 64, wn = (wave >> 1) * 64;
    f32x4 acc[4][4] = {};

    int sr = t >> 1;
    int sc = (t & 1) * 32;

    for (int k0 = 0; k0 < DD; k0 += 64) {
        const uint4* ga = (const uint4*)(A + (int64_t)(m0 + sr) * DD + k0 + sc);
        uint4 a0 = ga[0], a1 = ga[1], a2 = ga[2], a3 = ga[3];
        const uint4* gb = (const uint4*)(BT + (int64_t)(n0 + sr) * DD + k0 + sc);
        uint4 b0 = gb[0], b1 = gb[1], b2 = gb[2], b3 = gb[3];
        __syncthreads();
        *(uint4*)&As[sr][sc]      = a0;
        *(uint4*)&As[sr][sc + 8]  = a1;
        *(uint4*)&As[sr][sc + 16] = a2;
        *(uint4*)&As[sr][sc + 24] = a3;
        *(uint4*)&Bs[sr][sc]      = b0;
        *(uint4*)&Bs[sr][sc + 8]  = b1;
        *(uint4*)&Bs[sr][sc + 16] = b2;
        *(uint4*)&Bs[sr][sc + 24] = b3;
        __syncthreads();
#pragma unroll
        for (int kk = 0; kk < 64; kk += 32) {
            frag af[4], bf[4];
#pragma unroll
            for (int mi = 0; mi < 4; ++mi)
                af[mi] = *(const frag*)&As[wm + mi * 16 + l16][kk + quad * 8];
#pragma unroll
            for (int ni = 0; ni < 4; ++ni)
                bf[ni] = *(const frag*)&Bs[wn + ni * 16 + l16][kk + quad * 8];
#pragma unroll
            for (int mi = 0; mi < 4; ++mi)
#pragma unroll
                for (int ni = 0; ni < 4; ++ni)
                    acc[mi][ni] = __builtin_amdgcn_mfma_f32_16x16x32_bf16(
                        af[mi], bf[ni], acc[mi][ni], 0, 0, 0);
        }
    }
#pragma unroll
    for (int ni = 0; ni < 4; ++ni) {
        int col = n0 + wn + ni * 16 + l16;
        float bv = bias[col];
#pragma unroll
        for (int mi = 0; mi < 4; ++mi)
#pragma unroll
            for (int r = 0; r < 4; ++r) {
                int row = m0 + wm + mi * 16 + quad * 4 + r;
                C[(int64_t)row * N3H + col] = f2b(acc[mi][ni][r] + bv);
            }
    }
}

// ---------------- recurrence ----------------
// grid (mg=4, jb=64): linear id = mg + 4*jb -> each m-group's 64 blocks sit on
// XCDs {mg, mg+4} (i%8 round-robin). LDS: Wh[48][1032] bf16 (99KB).
// Flags: one 4B slot per block, 64B apart; group mg owns bar[mg*1024 + jb*16].

__global__ __launch_bounds__(256, 1) void k_recur(const uint16_t* __restrict__ gx,
                                                  const uint16_t* __restrict__ wht,
                                                  uint16_t* __restrict__ hbuf,
                                                  uint16_t* __restrict__ rhbuf,
                                                  unsigned int* __restrict__ bar,
                                                  float* __restrict__ out) {
    extern __shared__ uint16_t Wh[];           // 48 rows x 1032 (1024 + 8 pad)
    const int LDW = HH + 8;
    int mg = blockIdx.x;        // 0..3  (fast dim -> XCD pairing)
    int jb = blockIdx.y;        // 0..63
    int j0 = jb * 16;
    int m0 = mg * 64;
    int t = threadIdx.x, wave = t >> 6, lane = t & 63, quad = lane >> 4, l16 = lane & 15;

    // load w_h slice: gathered rows s*16+i  <-  wht row s*HH + j0 + i
    for (int c = t; c < 48 * 128; c += 256) {
        int row = c >> 7;
        int off = (c & 127) << 3;
        int s = row >> 4, i = row & 15;
        *(uint4*)(Wh + row * LDW + off) =
            *(const uint4*)(wht + (int64_t)(s * HH + j0 + i) * HH + off);
    }
    __syncthreads();

    float hp[4]   = {0.f, 0.f, 0.f, 0.f};
    float zg[4];
    float osum[4] = {0.f, 0.f, 0.f, 0.f};
    int brow = m0 + wave * 16 + quad * 4;
    int jcol = j0 + l16;
    const int jc4 = j0 + (l16 & ~3);         // 4-col pack base
    unsigned int* flags = bar + mg * 1024;   // 64 slots x 64B stride
    unsigned int phase = 0;

    // A-operand base (this lane's MFMA A rows) - read via sc0sc1 L3 loads
    const uint16_t* harow  = hbuf  + (int64_t)(m0 + wave * 16 + l16) * HH + quad * 8;
    const uint16_t* rharow = rhbuf + (int64_t)(m0 + wave * 16 + l16) * HH + quad * 8;

    // arrive: drain my data RMWs (syncthreads -> vmcnt(0)), then RMW my flag slot.
    auto bar_arrive = [&]() {
        __syncthreads();
        if (t == 0)
            (void)__hip_atomic_fetch_add(&flags[jb * 16], 1u, __ATOMIC_RELAXED,
                                         __HIP_MEMORY_SCOPE_AGENT);
    };
    // wait: wave0 polls all 64 slots in parallel with relaxed sc1 loads.
    // No fence after: h/rh reads bypass L2 (sc0sc1), gx is immutable.
    auto bar_wait = [&](unsigned int ph) {
        if (wave == 0) {
            long guard = 0;
            for (;;) {
                unsigned int v = __hip_atomic_load(&flags[lane * 16], __ATOMIC_RELAXED,
                                                   __HIP_MEMORY_SCOPE_AGENT);
                if (__all((int)(v >= ph))) break;
                __builtin_amdgcn_s_sleep(1);
                if (++guard > (1L << 13)) break;   // fail fast (absmax), never wedge
            }
        }
        __syncthreads();
    };

    // pack this lane's value with lanes l16^1, l16^2 -> one uint64 (4 adjacent
    // cols) exchanged to the coherence point by the (l16%4==0) lane.
    auto store4 = [&](uint16_t* base, int r, uint32_t mine) {
        uint32_t p2 = mine | (((uint32_t)__shfl_xor((int)mine, 1)) << 16);
        uint32_t hi = (uint32_t)__shfl_xor((int)p2, 2);
        if ((l16 & 3) == 0) {
            uint64_t p4 = (uint64_t)p2 | ((uint64_t)hi << 32);
            uint64_t* dst = (uint64_t*)base + (int64_t)(brow + r) * (HH / 4) + (jc4 >> 2);
            (void)__hip_atomic_exchange(dst, p4, __ATOMIC_RELAXED, __HIP_MEMORY_SCOPE_AGENT);
        }
    };

    for (int step = 0; step < TT; ++step) {
        // ---- barrier: h(step) fully written by all blocks in m-group ----
        if (step > 0) bar_arrive();

        // prefetch this step's gx scalars (immutable, cached; L2 stays warm all
        // 128 phases now) - issued between arrive and wait to hide under poll
        uint16_t gzv[4], grv[4], gav[4];
        {
            const uint16_t* gxrow = gx + (int64_t)step * BB * N3H;
#pragma unroll
            for (int r = 0; r < 4; ++r) {
                const uint16_t* g = gxrow + (int64_t)(brow + r) * N3H + jcol;
                gzv[r] = g[0]; grv[r] = g[HH]; gav[r] = g[2 * HH];
            }
        }

        if (step > 0) bar_wait(++phase);

        // ---- phase Z: h @ w_h_zr (acc0 = z-col, acc1 = r-col) ----
        {
            f32x4 acc0 = {}, acc1 = {};
            frag af[8];
#pragma unroll
            for (int kb = 0; kb < 4; ++kb) {
                load8_l3(harow + kb * 256, af);
#pragma unroll
                for (int j = 0; j < 8; ++j) {
                    int kk = kb * 8 + j;
                    frag b0 = *(const frag*)(Wh + (l16)      * LDW + kk * 32 + quad * 8);
                    frag b1 = *(const frag*)(Wh + (16 + l16) * LDW + kk * 32 + quad * 8);
                    acc0 = __builtin_amdgcn_mfma_f32_16x16x32_bf16(af[j], b0, acc0, 0, 0, 0);
                    acc1 = __builtin_amdgcn_mfma_f32_16x16x32_bf16(af[j], b1, acc1, 0, 0, 0);
                }
            }
#pragma unroll
            for (int r = 0; r < 4; ++r) {
                float zp = b2f(gzv[r]) + acc0[r];        // bias folded into gx
                float rp = b2f(grv[r]) + acc1[r];
                float z  = 1.f / (1.f + __expf(-zp));
                float rg = 1.f / (1.f + __expf(-rp));
                zg[r] = z;
                store4(rhbuf, r, f2b(rg * hp[r]));
            }
        }

        // ---- barrier: rh fully written by all blocks in m-group ----
        bar_arrive();
        bar_wait(++phase);

        // ---- phase A: rh @ w_h_a (acc2), gate + h update ----
        {
            f32x4 acc2 = {};
            frag af[8];
#pragma unroll
            for (int kb = 0; kb < 4; ++kb) {
                load8_l3(rharow + kb * 256, af);
#pragma unroll
                for (int j = 0; j < 8; ++j) {
                    int kk = kb * 8 + j;
                    frag b2 = *(const frag*)(Wh + (32 + l16) * LDW + kk * 32 + quad * 8);
                    acc2 = __builtin_amdgcn_mfma_f32_16x16x32_bf16(af[j], b2, acc2, 0, 0, 0);
                }
            }
#pragma unroll
            for (int r = 0; r < 4; ++r) {
                float a  = tanhf(b2f(gav[r]) + acc2[r]);
                float hn = (1.f - zg[r]) * hp[r] + zg[r] * a;
                osum[r] += hn;
                hp[r] = hn;
                store4(hbuf, r, f2b(hn));
            }
        }
    }
#pragma unroll
    for (int r = 0; r < 4; ++r)
        out[(int64_t)(brow + r) * HH + jcol] = osum[r];
}

// ---------------- launch ----------------

extern "C" void kernel_launch(void* const* d_in, const int* in_sizes, int n_in,
                              void* d_out, int out_size, void* d_ws, size_t ws_size,
                              hipStream_t stream) {
    const int*   x     = (const int*)d_in[0];
    const float* embed = (const float*)d_in[1];
    const float* w_i   = (const float*)d_in[2];
    const float* w_h   = (const float*)d_in[3];
    const float* bias  = (const float*)d_in[4];
    float* out = (float*)d_out;

    char* ws = (char*)d_ws;
    uint16_t* gx    = (uint16_t*)(ws);                 // 16384*3072*2 = 100663296
    uint16_t* wit   = (uint16_t*)(ws + 100663296);     // 3072*512*2  =   3145728
    uint16_t* wht   = (uint16_t*)(ws + 103809024);     // 3072*1024*2 =   6291456
    uint16_t* words = (uint16_t*)(ws + 110100480);     // 16384*512*2 =  16777216
    uint16_t* hbuf  = (uint16_t*)(ws + 126877696);     // 256*1024*2  =    524288
    uint16_t* rhbuf = (uint16_t*)(ws + 127401984);     // 256*1024*2  =    524288
    unsigned int* flags = (unsigned int*)(ws + 127926272); // 4*1024*4 = 16384

    k_gather<<<4096, 256, 0, stream>>>(x, embed, words);
    k_transpose<<<dim3(96, 16), dim3(32, 8), 0, stream>>>(w_i, wit, DD, N3H);
    k_transpose<<<dim3(96, 32), dim3(32, 8), 0, stream>>>(w_h, wht, HH, N3H);
    // zero hbuf + rhbuf + flags (contiguous 1048576 + 16384 bytes)
    k_zero<<<261, 256, 0, stream>>>((uint4*)(ws + 126877696), (1048576 + 16384) / 16);
    k_gemm_gx<<<dim3(24, 128), 256, 0, stream>>>(words, wit, bias, gx);
    k_recur<<<dim3(4, 64), 256, 48 * (HH + 8) * 2, stream>>>(gx, wht, hbuf, rhbuf, flags, out);
}